// Round 1
// 298.317 us; speedup vs baseline: 1.0213x; 1.0213x over previous
//
#include <hip/hip_runtime.h>
#include <hip/hip_bf16.h>

// Problem constants
#define BB   2
#define SEQ  2048
#define DIMD 2048
#define NHH  32
#define NKVV 8
#define HDD  64
#define QKVS 3072
// N_REP = 4

typedef __bf16 bf16x8 __attribute__((ext_vector_type(8)));
typedef float  floatx4 __attribute__((ext_vector_type(4)));

typedef __attribute__((address_space(1))) const void* gas_ptr;
typedef __attribute__((address_space(3))) void*       las_ptr;

#define MFMA16 __builtin_amdgcn_mfma_f32_16x16x32_bf16
#define CBAR() asm volatile("" ::: "memory")

__device__ __forceinline__ unsigned short f2bu(float f) {
    __hip_bfloat16 h = __float2bfloat16(f);
    return *reinterpret_cast<unsigned short*>(&h);
}

// ---------------------------------------------------------------------------
// Fused f32 -> bf16 conversion for all 5 inputs (one launch).
// ---------------------------------------------------------------------------
#define C_X  (8u  * 1024 * 1024)
#define C_WQ (4u  * 1024 * 1024)
#define C_WK (1u  * 1024 * 1024)
#define C_WV (1u  * 1024 * 1024)
#define C_WO (4u  * 1024 * 1024)
__global__ void cvt_all(const float* __restrict__ x,  const float* __restrict__ wq,
                        const float* __restrict__ wk, const float* __restrict__ wv,
                        const float* __restrict__ wo,
                        __hip_bfloat16* __restrict__ xb,
                        __hip_bfloat16* __restrict__ wqkv,
                        __hip_bfloat16* __restrict__ wob)
{
    unsigned i = (blockIdx.x * blockDim.x + threadIdx.x) * 4;
    const float* src; __hip_bfloat16* dst;
    if (i < C_X)                       { src = x  + i;                    dst = xb + i; }
    else if (i < C_X + C_WQ)           { unsigned o = i - C_X;            src = wq + o; dst = wqkv + o; }
    else if (i < C_X + C_WQ + C_WK)    { unsigned o = i - C_X - C_WQ;     src = wk + o; dst = wqkv + C_WQ + o; }
    else if (i < C_X + C_WQ + C_WK + C_WV) { unsigned o = i - C_X - C_WQ - C_WK; src = wv + o; dst = wqkv + C_WQ + C_WK + o; }
    else                               { unsigned o = i - C_X - C_WQ - C_WK - C_WV; if (o >= C_WO) return; src = wo + o; dst = wob + o; }
    float4 v = *reinterpret_cast<const float4*>(src);
    dst[0] = __float2bfloat16(v.x);
    dst[1] = __float2bfloat16(v.y);
    dst[2] = __float2bfloat16(v.z);
    dst[3] = __float2bfloat16(v.w);
}

// ---------------------------------------------------------------------------
// 8-phase 256-row-tile GEMM (m201/T3+T4 template, plain HIP).
// C[M,ldc] = A[M,K] @ W[N,K]^T, bf16 in, f32 acc. BK=64, dbuf LDS, 8 waves.
// BN=256: wave tile 128x64 (16-MFMA phases) - used for QKV (RoPE needs wave-N=64).
// BN=128: wave tile 128x32 ( 8-MFMA phases) - used for out-proj (grid=256=100% CU).
// Counted vmcnt(2) at each K-tile boundary; never drains to 0 in the loop.
// ---------------------------------------------------------------------------
template <typename OutT, bool ROPE, int BN>
__global__ __launch_bounds__(512, 2) void gemm8p(
    const __hip_bfloat16* __restrict__ Abf,
    const __hip_bfloat16* __restrict__ Wbf,
    OutT* __restrict__ C,
    int M, int N, int K, int ldc,
    const float* __restrict__ cosb, const float* __restrict__ sinb)
{
    constexpr int  NF = BN / 64;        // n-frags per wave (4 or 2)
    constexpr int  WN = BN / 4;         // wave n extent (64 or 32)
    constexpr bool B2 = (BN == 256);    // B halves need 2 loads/thread?
    constexpr int  HB = (BN / 2) * 64;  // elems per B half region

    const __bf16* Ag = reinterpret_cast<const __bf16*>(Abf);
    const __bf16* Wg = reinterpret_cast<const __bf16*>(Wbf);

    __shared__ __align__(16) __bf16 As[2][256 * 64];   // 64 KB
    __shared__ __align__(16) __bf16 Bs[2][BN * 64];    // 64/32 KB

    const int NT   = K >> 6;            // K-tiles of 64
    const int tid  = threadIdx.x;
    const int wid  = tid >> 6;
    const int lane = tid & 63;
    const int l15  = lane & 15;
    const int l4   = lane >> 4;
    const int wm   = wid >> 2;          // 2 M-waves
    const int wn   = wid & 3;           // 4 N-waves

    // XCD-aware bijective block swizzle (grid % 8 == 0 for both call sites)
    const int gx   = M >> 8;
    const int nwg  = (int)gridDim.x;
    const int orig = (int)blockIdx.x;
    const int wg   = (orig & 7) * (nwg >> 3) + (orig >> 3);
    const int bm   = (wg % gx) << 8;
    const int bn   = (wg / gx) * BN;

    // Staging source pointers; XOR swizzle pre-applied to the SOURCE column
    // (global_load_lds dest must stay linear: base + lane*16).
    const int r0 = tid >> 3;                       // row within 64-row stripe
    const int c0 = ((tid & 7) ^ (r0 & 7)) * 8;     // swizzled 16B chunk
    const __bf16* aS00 = Ag + (size_t)(bm + r0) * K + c0;
    const __bf16* aS01 = aS00 + (size_t)64  * K;
    const __bf16* aS10 = aS00 + (size_t)128 * K;
    const __bf16* aS11 = aS00 + (size_t)192 * K;
    const __bf16* bS00 = Wg + (size_t)(bn + r0) * K + c0;
    const __bf16* bS01 = bS00 + (size_t)64 * K;
    const __bf16* bS10 = bS00 + (size_t)(BN / 2) * K;
    const __bf16* bS11 = bS10 + (size_t)64 * K;

    bf16x8 af[4][2], b01[2][2], b23[2][2];
    floatx4 acc[8][NF] = {};

    auto stage2 = [&](const __bf16* s0, const __bf16* s1, __bf16* d, int kt) {
        int k0 = (kt < NT ? kt : NT - 1) << 6;     // clamp tail (harmless reload)
        __builtin_amdgcn_global_load_lds((gas_ptr)(s0 + k0), (las_ptr)(d + tid * 8), 16, 0, 0);
        if (s1)
        __builtin_amdgcn_global_load_lds((gas_ptr)(s1 + k0), (las_ptr)(d + 4096 + tid * 8), 16, 0, 0);
    };
    auto lda = [&](int buf, int mbase) {
        #pragma unroll
        for (int mi = 0; mi < 4; ++mi)
            #pragma unroll
            for (int kk = 0; kk < 2; ++kk) {
                int row = wm * 128 + (mbase + mi) * 16 + l15;
                int ch  = ((kk * 4 + l4) ^ (row & 7)) * 8;
                af[mi][kk] = *reinterpret_cast<const bf16x8*>(&As[buf][row * 64 + ch]);
            }
    };
    auto ldb = [&](int buf, bf16x8 (&regs)[2][2], int nbase) {
        #pragma unroll
        for (int ni = 0; ni < 2; ++ni)
            #pragma unroll
            for (int kk = 0; kk < 2; ++kk) {
                int row = wn * WN + (nbase + ni) * 16 + l15;
                int ch  = ((kk * 4 + l4) ^ (row & 7)) * 8;
                regs[ni][kk] = *reinterpret_cast<const bf16x8*>(&Bs[buf][row * 64 + ch]);
            }
    };
    auto mmBoth = [&](int mbase, bf16x8 (&bregs)[2][2], int nb) {   // 16 MFMA
        #pragma unroll
        for (int mi = 0; mi < 4; ++mi)
            #pragma unroll
            for (int ni = 0; ni < 2; ++ni) {
                acc[mbase + mi][nb + ni] = MFMA16(af[mi][0], bregs[ni][0], acc[mbase + mi][nb + ni], 0, 0, 0);
                acc[mbase + mi][nb + ni] = MFMA16(af[mi][1], bregs[ni][1], acc[mbase + mi][nb + ni], 0, 0, 0);
            }
    };
    auto mmOne = [&](int mbase, int kk) {                           // 8 MFMA
        #pragma unroll
        for (int mi = 0; mi < 4; ++mi)
            #pragma unroll
            for (int ni = 0; ni < 2; ++ni)
                acc[mbase + mi][ni] = MFMA16(af[mi][kk], b01[ni][kk], acc[mbase + mi][ni], 0, 0, 0);
    };

    // One K-tile = 4 phases. Staging of tile t+1 spans t-1.P4 .. t.P3, so the
    // boundary vmcnt(2) leaves only P4's (tile t+2 h0) loads in flight.
    auto ktile = [&](int cur, int t) {
        // ---- P1: lds A-lo + B01, stage A-h1 of t+1
        lda(cur, 0);
        ldb(cur, b01, 0);
        stage2(aS10, aS11, &As[cur ^ 1][8192], t + 1);
        CBAR(); __builtin_amdgcn_s_barrier(); CBAR();
        asm volatile("s_waitcnt lgkmcnt(0)" ::: "memory");
        __builtin_amdgcn_sched_barrier(0);
        __builtin_amdgcn_s_setprio(1);
        if constexpr (B2) mmBoth(0, b01, 0); else mmOne(0, 0);
        __builtin_amdgcn_s_setprio(0);
        CBAR(); __builtin_amdgcn_s_barrier(); CBAR();
        // ---- P2: lds B23 (BN=256), stage B-h0 of t+1
        if constexpr (B2) ldb(cur, b23, 2);
        stage2(bS00, B2 ? bS01 : (const __bf16*)nullptr, &Bs[cur ^ 1][0], t + 1);
        CBAR(); __builtin_amdgcn_s_barrier(); CBAR();
        asm volatile("s_waitcnt lgkmcnt(0)" ::: "memory");
        __builtin_amdgcn_sched_barrier(0);
        __builtin_amdgcn_s_setprio(1);
        if constexpr (B2) mmBoth(0, b23, 2); else mmOne(0, 1);
        __builtin_amdgcn_s_setprio(0);
        CBAR(); __builtin_amdgcn_s_barrier(); CBAR();
        // ---- P3: lds A-hi, stage B-h1 of t+1
        lda(cur, 4);
        stage2(bS10, B2 ? bS11 : (const __bf16*)nullptr, &Bs[cur ^ 1][HB], t + 1);
        CBAR(); __builtin_amdgcn_s_barrier(); CBAR();
        asm volatile("s_waitcnt lgkmcnt(0)" ::: "memory");
        __builtin_amdgcn_sched_barrier(0);
        __builtin_amdgcn_s_setprio(1);
        if constexpr (B2) mmBoth(4, b23, 2); else mmOne(4, 1);
        __builtin_amdgcn_s_setprio(0);
        CBAR(); __builtin_amdgcn_s_barrier(); CBAR();
        // ---- P4: stage A-h0 of t+2 (region free after P3), counted vmcnt
        stage2(aS00, aS01, &As[cur][0], t + 2);
        CBAR(); __builtin_amdgcn_s_barrier(); CBAR();
        __builtin_amdgcn_s_setprio(1);
        if constexpr (B2) mmBoth(4, b01, 0); else mmOne(4, 0);
        __builtin_amdgcn_s_setprio(0);
        asm volatile("s_waitcnt vmcnt(2)" ::: "memory");
        CBAR(); __builtin_amdgcn_s_barrier(); CBAR();
    };

    // Prologue: tile0 fully + tile1.h0 (matches steady-state boundary invariant)
    stage2(aS00, aS01, &As[0][0],    0);
    stage2(aS10, aS11, &As[0][8192], 0);
    stage2(bS00, B2 ? bS01 : (const __bf16*)nullptr, &Bs[0][0],  0);
    stage2(bS10, B2 ? bS11 : (const __bf16*)nullptr, &Bs[0][HB], 0);
    stage2(aS00, aS01, &As[1][0],    1);
    asm volatile("s_waitcnt vmcnt(2)" ::: "memory");
    CBAR(); __builtin_amdgcn_s_barrier(); CBAR();

    #pragma unroll 1
    for (int t = 0; t < NT; t += 2) {
        ktile(0, t);
        ktile(1, t + 1);
    }

    // ---- Epilogue
    if constexpr (ROPE) {
        bool do_rope = (bn + wn * 64) < 2560;     // q|k sections; wave-uniform
        #pragma unroll
        for (int mi = 0; mi < 8; ++mi) {
            #pragma unroll
            for (int r = 0; r < 4; ++r) {
                int row = bm + wm * 128 + mi * 16 + l4 * 4 + r;
                int s   = row & (SEQ - 1);
                #pragma unroll
                for (int j = 0; j < 2; ++j) {
                    float x1 = acc[mi][j][r], x2 = acc[mi][j + 2][r];
                    if (do_rope) {
                        float cf = cosb[s * 32 + j * 16 + l15];
                        float sf = sinb[s * 32 + j * 16 + l15];
                        float o1 = x1 * cf - x2 * sf;
                        float o2 = x2 * cf + x1 * sf;
                        x1 = o1; x2 = o2;
                    }
                    int col = bn + wn * 64 + j * 16 + l15;
                    C[(size_t)row * ldc + col]      = __float2bfloat16(x1);
                    C[(size_t)row * ldc + col + 32] = __float2bfloat16(x2);
                }
            }
        }
    } else {
        #pragma unroll
        for (int mi = 0; mi < 8; ++mi)
            #pragma unroll
            for (int ni = 0; ni < NF; ++ni)
                #pragma unroll
                for (int r = 0; r < 4; ++r) {
                    int row = bm + wm * 128 + mi * 16 + l4 * 4 + r;
                    int col = bn + wn * WN + ni * 16 + l15;
                    if constexpr (sizeof(OutT) == 4)
                        C[(size_t)row * ldc + col] = acc[mi][ni][r];
                    else
                        C[(size_t)row * ldc + col] = __float2bfloat16(acc[mi][ni][r]);
                }
    }
}

// ---------------------------------------------------------------------------
// V transpose: vT[b][kvh][d][s] <- qkv v-section [b*S+s][2560 + kvh*64 + d]
// ---------------------------------------------------------------------------
__global__ void transpose_v(const __hip_bfloat16* __restrict__ qkv,
                            unsigned short* __restrict__ vT)
{
    __shared__ unsigned short T[64][68];
    int s0  = blockIdx.x * 64;
    int kvh = blockIdx.y;
    int b   = blockIdx.z;
    int tid = threadIdx.x;

    int srow = tid >> 2, dg = (tid & 3) * 16;
    const unsigned short* src = reinterpret_cast<const unsigned short*>(qkv)
        + (size_t)(b * SEQ + s0 + srow) * QKVS + 2560 + kvh * 64 + dg;
    #pragma unroll
    for (int i = 0; i < 4; ++i)
        *reinterpret_cast<ushort4*>(&T[srow][dg + i * 4]) =
            *reinterpret_cast<const ushort4*>(src + i * 4);
    __syncthreads();

    int drow = tid >> 2, sg = (tid & 3) * 16;
    unsigned short* dst = vT + ((size_t)(b * NKVV + kvh) * 64 + drow) * SEQ + s0 + sg;
    #pragma unroll
    for (int i = 0; i < 4; ++i) {
        ushort4 u;
        u.x = T[sg + i * 4 + 0][drow];
        u.y = T[sg + i * 4 + 1][drow];
        u.z = T[sg + i * 4 + 2][drow];
        u.w = T[sg + i * 4 + 3][drow];
        *reinterpret_cast<ushort4*>(dst + i * 4) = u;
    }
}

// ---------------------------------------------------------------------------
// MFMA flash attention, doc+causal, doc-skip at chunk level. (unchanged)
// ---------------------------------------------------------------------------
__global__ __launch_bounds__(256) void attn_mfma(
    const __hip_bfloat16* __restrict__ qkv,  // [B*S][3072]: q | k | v
    const unsigned short* __restrict__ vT,   // [B][NKV][64][S]
    const int* __restrict__ doc,             // [B][S]
    __hip_bfloat16* __restrict__ ob)         // [B*S][NH*64]
{
    int qblk = (int)gridDim.x - 1 - (int)blockIdx.x;   // heavy blocks first
    int h    = blockIdx.y;
    int b    = blockIdx.z;
    int kvh  = h >> 2;
    int tid  = threadIdx.x;
    int wv   = tid >> 6;
    int lane = tid & 63;
    int l15  = lane & 15;
    int l4   = lane >> 4;
    int q0   = qblk * 128;
    int qw   = q0 + wv * 32;

    __shared__ unsigned short Ks[64 * 64];    // [key][dim], swizzled chunks
    __shared__ unsigned short Vts[64 * 64];   // [dim][key], swizzled chunks
    __shared__ unsigned short Pb[4][32][76];  // per-wave P tile
    __shared__ int kdoc[64];

    const unsigned short* qus = reinterpret_cast<const unsigned short*>(qkv);
    const unsigned short* kus = qus + 2048;

    bf16x8 aq[2][2];
    #pragma unroll
    for (int qt = 0; qt < 2; ++qt) {
        const unsigned short* qrow = qus + (size_t)(b * SEQ + qw + qt * 16 + l15) * QKVS + h * HDD;
        aq[qt][0] = *reinterpret_cast<const bf16x8*>(qrow + l4 * 8);
        aq[qt][1] = *reinterpret_cast<const bf16x8*>(qrow + 32 + l4 * 8);
    }
    int qd[2][4];
    #pragma unroll
    for (int qt = 0; qt < 2; ++qt)
        #pragma unroll
        for (int r = 0; r < 4; ++r)
            qd[qt][r] = doc[b * SEQ + qw + qt * 16 + l4 * 4 + r];
    int qd_w   = doc[b * SEQ + qw];
    int qd_blk = doc[b * SEQ + q0];

    float mrow[2][4], lrow[2][4];
    #pragma unroll
    for (int qt = 0; qt < 2; ++qt)
        #pragma unroll
        for (int r = 0; r < 4; ++r) { mrow[qt][r] = -1e30f; lrow[qt][r] = 0.f; }
    floatx4 accO[2][4] = {};

    int slot0 = tid, slot1 = tid + 256;
    int row0 = slot0 >> 3, g0 = (slot0 & 7) ^ (row0 & 7);
    int row1 = slot1 >> 3, g1 = (slot1 & 7) ^ (row1 & 7);
    const unsigned short* vtb = vT + ((size_t)(b * NKVV + kvh) * 64) * SEQ;

    int kc_end = 2 * qblk + 1;
    for (int kc = 0; kc <= kc_end; ++kc) {
        int k0 = kc * 64;
        int kd_last = doc[b * SEQ + k0 + 63];
        if (kd_last < qd_blk) continue;        // block-uniform doc skip

        __syncthreads();
        __builtin_amdgcn_global_load_lds(
            (gas_ptr)(kus + (size_t)(b * SEQ + k0 + row0) * QKVS + kvh * HDD + g0 * 8),
            (las_ptr)(Ks + slot0 * 8), 16, 0, 0);
        __builtin_amdgcn_global_load_lds(
            (gas_ptr)(kus + (size_t)(b * SEQ + k0 + row1) * QKVS + kvh * HDD + g1 * 8),
            (las_ptr)(Ks + slot1 * 8), 16, 0, 0);
        __builtin_amdgcn_global_load_lds(
            (gas_ptr)(vtb + (size_t)row0 * SEQ + k0 + g0 * 8),
            (las_ptr)(Vts + slot0 * 8), 16, 0, 0);
        __builtin_amdgcn_global_load_lds(
            (gas_ptr)(vtb + (size_t)row1 * SEQ + k0 + g1 * 8),
            (las_ptr)(Vts + slot1 * 8), 16, 0, 0);
        if (tid < 64) kdoc[tid] = doc[b * SEQ + k0 + tid];
        __syncthreads();

        if (k0 <= qw + 31 && kd_last >= qd_w) {   // wave-uniform compute skip
            #pragma unroll
            for (int qt = 0; qt < 2; ++qt) {
                float s[4][4];
                #pragma unroll
                for (int t = 0; t < 4; ++t) {
                    int krow = t * 16 + l15;
                    bf16x8 bk0 = *reinterpret_cast<const bf16x8*>(Ks + krow * 64 + ((l4 ^ (krow & 7)) * 8));
                    bf16x8 bk1 = *reinterpret_cast<const bf16x8*>(Ks + krow * 64 + ((((l4 + 4)) ^ (krow & 7)) * 8));
                    floatx4 acc = {};
                    acc = MFMA16(aq[qt][0], bk0, acc, 0, 0, 0);
                    acc = MFMA16(aq[qt][1], bk1, acc, 0, 0, 0);
                    int key = k0 + krow;
                    int kd  = kdoc[krow];
                    #pragma unroll
                    for (int r = 0; r < 4; ++r) {
                        int qrow = qw + qt * 16 + l4 * 4 + r;
                        bool valid = (kd == qd[qt][r]) && (key <= qrow);
                        s[t][r] = valid ? acc[r] * 0.125f : -1e30f;
                    }
                }
                #pragma unroll
                for (int r = 0; r < 4; ++r) {
                    float pm = fmaxf(fmaxf(s[0][r], s[1][r]), fmaxf(s[2][r], s[3][r]));
                    pm = fmaxf(pm, __shfl_xor(pm, 1));
                    pm = fmaxf(pm, __shfl_xor(pm, 2));
                    pm = fmaxf(pm, __shfl_xor(pm, 4));
                    pm = fmaxf(pm, __shfl_xor(pm, 8));
                    float mnew = fmaxf(mrow[qt][r], pm);
                    float alpha = __expf(mrow[qt][r] - mnew);
                    mrow[qt][r] = mnew;
                    float ps = 0.f;
                    #pragma unroll
                    for (int t = 0; t < 4; ++t) {
                        float p = (s[t][r] <= -1e29f) ? 0.f : __expf(s[t][r] - mnew);
                        Pb[wv][qt * 16 + l4 * 4 + r][t * 16 + l15] = f2bu(p);
                        ps += p;
                    }
                    ps += __shfl_xor(ps, 1);
                    ps += __shfl_xor(ps, 2);
                    ps += __shfl_xor(ps, 4);
                    ps += __shfl_xor(ps, 8);
                    lrow[qt][r] = lrow[qt][r] * alpha + ps;
                    #pragma unroll
                    for (int t = 0; t < 4; ++t) accO[qt][t][r] *= alpha;
                }
            }
            #pragma unroll
            for (int qt = 0; qt < 2; ++qt) {
                bf16x8 ap0 = *reinterpret_cast<const bf16x8*>(&Pb[wv][qt * 16 + l15][l4 * 8]);
                bf16x8 ap1 = *reinterpret_cast<const bf16x8*>(&Pb[wv][qt * 16 + l15][32 + l4 * 8]);
                #pragma unroll
                for (int t = 0; t < 4; ++t) {
                    int vrow = t * 16 + l15;
                    bf16x8 bv0 = *reinterpret_cast<const bf16x8*>(Vts + vrow * 64 + ((l4 ^ (vrow & 7)) * 8));
                    bf16x8 bv1 = *reinterpret_cast<const bf16x8*>(Vts + vrow * 64 + ((((l4 + 4)) ^ (vrow & 7)) * 8));
                    accO[qt][t] = MFMA16(ap0, bv0, accO[qt][t], 0, 0, 0);
                    accO[qt][t] = MFMA16(ap1, bv1, accO[qt][t], 0, 0, 0);
                }
            }
        }
    }

    #pragma unroll
    for (int qt = 0; qt < 2; ++qt)
        #pragma unroll
        for (int r = 0; r < 4; ++r) {
            float inv = 1.0f / lrow[qt][r];
            size_t base = (size_t)(b * SEQ + qw + qt * 16 + l4 * 4 + r) * (NHH * HDD) + h * HDD;
            #pragma unroll
            for (int t = 0; t < 4; ++t)
                ob[base + t * 16 + l15] = __float2bfloat16(accO[qt][t][r] * inv);
        }
}

// ---------------------------------------------------------------------------
extern "C" void kernel_launch(void* const* d_in, const int* in_sizes, int n_in,
                              void* d_out, int out_size, void* d_ws, size_t ws_size,
                              hipStream_t stream) {
    const float* x  = (const float*)d_in[0];
    const float* rc = (const float*)d_in[1];
    const float* rs = (const float*)d_in[2];
    const int*   dc = (const int*)d_in[3];
    const float* Wq = (const float*)d_in[4];
    const float* Wk = (const float*)d_in[5];
    const float* Wv = (const float*)d_in[6];
    const float* Wo = (const float*)d_in[7];
    float* out = (float*)d_out;

    const int M    = BB * SEQ;        // 4096
    const int KVD  = NKVV * HDD;      // 512
    const int QKVN = DIMD + 2 * KVD;  // 3072

    char* ws = (char*)d_ws;
    size_t off = 0;
    auto alloc = [&](size_t elems) { __hip_bfloat16* p = (__hip_bfloat16*)(ws + off); off += elems * 2; return p; };
    __hip_bfloat16* xb   = alloc((size_t)M * DIMD);      // 16 MB
    __hip_bfloat16* wqkv = alloc((size_t)QKVN * DIMD);   // 12 MB
    __hip_bfloat16* wob  = alloc((size_t)DIMD * DIMD);   //  8 MB
    __hip_bfloat16* qkv  = alloc((size_t)M * QKVN);      // 24 MB
    __hip_bfloat16* abuf = alloc((size_t)M * DIMD);      // 16 MB
    unsigned short* vtb  = (unsigned short*)alloc((size_t)BB * NKVV * HDD * SEQ); // 4 MB

    // one fused f32->bf16 conversion launch
    {
        unsigned total4 = (C_X + C_WQ + C_WK + C_WV + C_WO) / 4;
        cvt_all<<<dim3((total4 + 255) / 256), 256, 0, stream>>>(
            x, Wq, Wk, Wv, Wo, xb, wqkv, wob);
    }

    // fused QKV projection with RoPE epilogue: [4096][3072], 256x256 tiles (192 blocks)
    gemm8p<__hip_bfloat16, true, 256><<<dim3((M / 256) * (QKVN / 256)), 512, 0, stream>>>(
        xb, wqkv, qkv, M, QKVN, DIMD, QKVN, rc, rs);

    // V transpose for PV B-fragments
    transpose_v<<<dim3(SEQ / 64, NKVV, BB), 256, 0, stream>>>(qkv, vtb);

    // attention (MFMA, doc-skip)
    attn_mfma<<<dim3(SEQ / 128, NHH, BB), 256, 0, stream>>>(qkv, vtb, dc, abuf);

    // output projection (f32 out), 256x128 tiles -> 256 blocks = full CU fill
    gemm8p<float, false, 128><<<dim3((M / 256) * (DIMD / 128)), 512, 0, stream>>>(
        abuf, wob, out, M, DIMD, DIMD, DIMD, nullptr, nullptr);
}